// Round 8
// baseline (318.088 us; speedup 1.0000x reference)
//
#include <hip/hip_runtime.h>
#include <hip/hip_bf16.h>

// Problem constants (fixed by the reference)
#define CS     128
#define EDIM   256
#define NBATCH 2
#define TLEN   8192
#define NCHUNK 64
#define LEXT   1024
#define KSEL   7

typedef __attribute__((ext_vector_type(8))) short   short8;   // 8 bf16 = 4 VGPR (MFMA A/B frag)
typedef __attribute__((ext_vector_type(4))) float   floatx4;  // MFMA C/D frag

__device__ inline short bf16_of(float f) {
    __hip_bfloat16 h = __float2bfloat16(f);
    return *(short*)&h;
}
__device__ inline float f_of_bf16(short s) {
    __hip_bfloat16 h = *(__hip_bfloat16*)&s;
    return __bfloat162float(h);
}

// async global->LDS, 16B per lane; LDS dest = wave-uniform base + lane*16
__device__ inline void gl_lds16(const void* g, void* l) {
    __builtin_amdgcn_global_load_lds(
        (const __attribute__((address_space(1))) unsigned int*)g,
        (__attribute__((address_space(3))) unsigned int*)l, 16, 0, 0);
}

// ---------------------------------------------------------------------------
// Stage A1: normalize rows, split to bf16 hi/lo (for scores). One wave/row.
// ---------------------------------------------------------------------------
__global__ __launch_bounds__(256) void normsplit_kernel(const float* __restrict__ x,
                                                        short* __restrict__ cn_hi,
                                                        short* __restrict__ cn_lo) {
    int row  = blockIdx.x * 4 + (threadIdx.x >> 6);
    int lane = threadIdx.x & 63;
    const float4 v = ((const float4*)(x + (size_t)row * EDIM))[lane];
    float s = v.x * v.x + v.y * v.y + v.z * v.z + v.w * v.w;
#pragma unroll
    for (int off = 1; off < 64; off <<= 1) s += __shfl_xor(s, off);
    float r = 1.0f / (sqrtf(s) + 1e-6f);

    float c[4] = {v.x * r, v.y * r, v.z * r, v.w * r};
    short hs[4], ls[4];
#pragma unroll
    for (int q = 0; q < 4; ++q) {
        hs[q] = bf16_of(c[q]);
        ls[q] = bf16_of(c[q] - f_of_bf16(hs[q]));
    }
    size_t o = (size_t)row * EDIM + lane * 4;
    *(short4*)(cn_hi + o) = make_short4(hs[0], hs[1], hs[2], hs[3]);
    *(short4*)(cn_lo + o) = make_short4(ls[0], ls[1], ls[2], ls[3]);
}

// ---------------------------------------------------------------------------
// Stage A2: down_proj -> bf16 (single-pass: out GEMM needs hi only)
// ---------------------------------------------------------------------------
__global__ __launch_bounds__(256) void dp_split_kernel(const float* __restrict__ dp,
                                                       short* __restrict__ dph) {
    int idx = (blockIdx.x * 256 + threadIdx.x) * 4;
    float4 v = *(const float4*)(dp + idx);
    *(short4*)(dph + idx) = make_short4(bf16_of(v.x), bf16_of(v.y), bf16_of(v.z), bf16_of(v.w));
}

// ---------------------------------------------------------------------------
// Stage A3: transpose x to [b][e][t], bf16 (hi only, for out B-operand)
// ---------------------------------------------------------------------------
__global__ __launch_bounds__(256) void xt_split_kernel(const float* __restrict__ x,
                                                       short* __restrict__ xth) {
    __shared__ float tile[64][68];
    const int e0 = blockIdx.x * 64, t0 = blockIdx.y * 64, b = blockIdx.z;
    const int tid = threadIdx.x;
    const int cr = tid >> 4, cc = (tid & 15) * 4;
#pragma unroll
    for (int p = 0; p < 4; ++p) {
        int r = cr + p * 16;
        float4 v = *(const float4*)(x + ((size_t)(b * TLEN + t0 + r)) * EDIM + e0 + cc);
        *(float4*)&tile[r][cc] = v;
    }
    __syncthreads();
    const int e = tid >> 2, toff = (tid & 3) * 16;
    short hs[16];
#pragma unroll
    for (int q = 0; q < 16; ++q) hs[q] = bf16_of(tile[toff + q][e]);
    size_t o = ((size_t)(b * EDIM + e0 + e)) * TLEN + t0 + toff;
#pragma unroll
    for (int q4 = 0; q4 < 4; ++q4)
        *(short4*)(xth + o + q4 * 4) = make_short4(hs[q4*4], hs[q4*4+1], hs[q4*4+2], hs[q4*4+3]);
}

// ---------------------------------------------------------------------------
// Stage B v4: j-cache-resident split-bf16 MFMA cosine scores.
// Block = 16 consecutive pairs of the column-major pair list (j outer,
// i ascending): 2016 pairs/batch = 126 blocks x 16, grid (126,2) ~ 1.0
// grid-wave, perfectly balanced. The j-chunk (full K=256, hi+lo) lives in
// a 144KB LDS cache (row pitch 72 shorts = 144B: 16B-aligned b128 reads,
// 2-way banks = free); staged once per j-group via VGPR round-trip.
// A (i-chunk) frags are register-direct global loads. The 8-kstep MFMA
// loop has NO barriers (LDS is read-only) — kills the r3 vmcnt(0)-drain
// plateau (~1 barrier/pair vs 16). 4 waves each own 32 rows x 128 cols
// (acc[2][8]). Numerics: identical MFMA sequence per acc element as r3
// -> sims bit-identical -> selection unchanged.
// ---------------------------------------------------------------------------
__global__ __launch_bounds__(256) void scores_mfma(const short* __restrict__ cn_hi,
                                                   const short* __restrict__ cn_lo,
                                                   float* __restrict__ scores) {
    __shared__ short  jc[8 * 128 * 72];   // [ks][d][hi 32 | lo 32 | pad 8] = 144 KB
    __shared__ double sred[2][4];

    const int b   = blockIdx.y;
    const int tid = threadIdx.x;
    const int w   = tid >> 6, lane = tid & 63;
    const int quad = lane >> 4, l15 = lane & 15;

    const int q0 = blockIdx.x * 16;
    int j = 0, jcur = -1;

    for (int pp = 0; pp < 16; ++pp) {
        const int q = q0 + pp;
        while ((j + 1) * (126 - j) / 2 <= q) ++j;     // off(j+1) = (j+1)(126-j)/2
        const int i = j + 1 + (q - j * (127 - j) / 2);

        if (j != jcur) {
            __syncthreads();   // prior pair's readers done with jc
            for (int u = 0; u < 8; ++u) {
                int idx = u * 256 + tid;               // [0,2048)
                int hl = idx >> 10, ks = (idx >> 7) & 7, d = idx & 127;
                const short* src = (hl ? cn_lo : cn_hi)
                                   + ((size_t)(b * TLEN + j * CS + d) * EDIM + ks * 32);
                short* dst = &jc[(ks * 128 + d) * 72 + hl * 32];
#pragma unroll
                for (int v = 0; v < 4; ++v)
                    *(int4*)(dst + v * 8) = *(const int4*)(src + v * 8);
            }
            __syncthreads();
            jcur = j;
        }

        floatx4 acc[2][8];
#pragma unroll
        for (int rt = 0; rt < 2; ++rt)
#pragma unroll
            for (int ct = 0; ct < 8; ++ct) acc[rt][ct] = (floatx4){0.f, 0.f, 0.f, 0.f};

        const size_t abase = ((size_t)b * TLEN + (size_t)i * CS + w * 32) * EDIM;

#pragma unroll
        for (int ks = 0; ks < 8; ++ks) {
            short8 ah[2], al[2];
#pragma unroll
            for (int rt = 0; rt < 2; ++rt) {
                size_t off = abase + (size_t)(rt * 16 + l15) * EDIM + ks * 32 + quad * 8;
                ah[rt] = *(const short8*)(cn_hi + off);
                al[rt] = *(const short8*)(cn_lo + off);
            }
#pragma unroll
            for (int ct = 0; ct < 8; ++ct) {
                const short* pb = &jc[(ks * 128 + ct * 16 + l15) * 72 + quad * 8];
                short8 bh = *(const short8*)pb;
                short8 bl = *(const short8*)(pb + 32);
#pragma unroll
                for (int rt = 0; rt < 2; ++rt) {
                    acc[rt][ct] = __builtin_amdgcn_mfma_f32_16x16x32_bf16(ah[rt], bh, acc[rt][ct], 0, 0, 0);
                    acc[rt][ct] = __builtin_amdgcn_mfma_f32_16x16x32_bf16(ah[rt], bl, acc[rt][ct], 0, 0, 0);
                    acc[rt][ct] = __builtin_amdgcn_mfma_f32_16x16x32_bf16(al[rt], bh, acc[rt][ct], 0, 0, 0);
                }
            }
        }

        // epilogue: wave w holds rows w*32 + rt*16 + quad*4 + reg, cols ct*16+l15.
        // rowmax over all 128 cols (ct regs + l15 lanes), then double-sum rows.
        double dsum = 0.0;
#pragma unroll
        for (int rt = 0; rt < 2; ++rt) {
            float m[4];
#pragma unroll
            for (int reg = 0; reg < 4; ++reg) {
                float mm = acc[rt][0][reg];
#pragma unroll
                for (int ct = 1; ct < 8; ++ct) mm = fmaxf(mm, acc[rt][ct][reg]);
                m[reg] = mm;
            }
#pragma unroll
            for (int off = 1; off < 16; off <<= 1)
#pragma unroll
                for (int reg = 0; reg < 4; ++reg) m[reg] = fmaxf(m[reg], __shfl_xor(m[reg], off));
#pragma unroll
            for (int reg = 0; reg < 4; ++reg) dsum += (double)m[reg];
        }
        dsum += __shfl_xor(dsum, 16);   // sum over quad (rows quad*4+reg distinct)
        dsum += __shfl_xor(dsum, 32);

        if (lane == 0) sred[pp & 1][w] = dsum;
        __syncthreads();
        if (tid == 0)
            scores[(b * NCHUNK + i) * NCHUNK + j] =
                (float)(sred[pp & 1][0] + sred[pp & 1][1] + sred[pp & 1][2] + sred[pp & 1][3]);
    }
}

// ---------------------------------------------------------------------------
// Stage C: top-7 selection + weights (tiny, serial) — unchanged
// ---------------------------------------------------------------------------
__global__ void topk_kernel(const float* __restrict__ scores,
                            int* __restrict__ ext_idx,
                            float* __restrict__ ext_w) {
    int tid = threadIdx.x;
    if (tid >= NBATCH * NCHUNK) return;
    int b = tid >> 6, i = tid & 63;
    const float* srow = scores + (b * NCHUNK + i) * NCHUNK;

    int nsel = i < KSEL ? i : KSEL;
    float vals[KSEL];
    int   idxs[KSEL];
    unsigned long long used = 0ull;
    for (int s = 0; s < nsel; ++s) {
        float best = -3.0e38f;
        int   bj = 0;
        for (int jj = 0; jj < i; ++jj) {
            if ((used >> jj) & 1ull) continue;
            float v = srow[jj];
            if (v > best) { best = v; bj = jj; }
        }
        used |= 1ull << bj;
        vals[s] = best;
        idxs[s] = bj;
    }
    float vmin = (nsel > 0) ? vals[nsel - 1] : 0.0f;
    float inv  = 1.0f / (vmin + 1e-6f);
    int shift  = KSEL - nsel;
    for (int s = 0; s < KSEL; ++s) {
        int t = s - shift;
        int o = (b * NCHUNK + i) * KSEL + s;
        if (t >= 0) { ext_idx[o] = idxs[t]; ext_w[o] = vals[t] * inv; }
        else        { ext_idx[o] = -1;      ext_w[o] = 0.0f; }
    }
}

// ---------------------------------------------------------------------------
// Stage D v3: out = dp @ ext + chunk, single-pass bf16 MFMA (r7, passed)
// ---------------------------------------------------------------------------
__global__ __launch_bounds__(256) void out_mfma(const float* __restrict__ x,
                                                const short* __restrict__ dph,
                                                const short* __restrict__ xth,
                                                const int* __restrict__ ext_idx,
                                                const float* __restrict__ ext_w,
                                                float* __restrict__ out) {
    __shared__ short As[2][128 * 32];   // [buf][c][k]  8 KB each
    __shared__ short Bs[2][128 * 32];   // [buf][e][k]  8 KB each
    __shared__ int   sjj[8];
    __shared__ float sww[8];
    __shared__ int   slist[8], sslot[8], snum;
    __shared__ float swei[8];

    const int eq = blockIdx.x, n = blockIdx.y, b = blockIdx.z;
    const int e0 = eq * 128;
    const int tid  = threadIdx.x;
    const int w    = tid >> 6, lane = tid & 63;
    const int wr   = w >> 1, wc = w & 1;
    const int quad = lane >> 4, l15 = lane & 15;
    const int rr   = lane >> 2;
    const int c16  = (lane & 3) * 8;

    if (tid < KSEL) {
        sjj[tid] = ext_idx[(b * NCHUNK + n) * KSEL + tid];
        sww[tid] = ext_w [(b * NCHUNK + n) * KSEL + tid];
    }
    if (tid == KSEL) { sjj[KSEL] = n; sww[KSEL] = 1.0f; }
    __syncthreads();
    if (tid == 0) {
        int c = 0;
        for (int s = 0; s < 8; ++s)
            if (sjj[s] >= 0) { slist[c] = sjj[s]; sslot[c] = s; swei[c] = sww[s]; ++c; }
        snum = c;
    }
    __syncthreads();
    const int NS = snum * 4;

    auto stage = [&](int st, int bf) {
        int sv = st >> 2, kk = st & 3;
        if (w < 2) {
            const short* gsrc = dph + (size_t)(sslot[sv] * 128 + kk * 32) + c16;
#pragma unroll
            for (int t = 0; t < 4; ++t)
                gl_lds16(gsrc + (size_t)(w * 64 + t * 16 + rr) * LEXT,
                         &As[bf][(w * 64 + t * 16) * 32]);
        } else {
            const short* gsrc = xth + ((size_t)(b * EDIM + e0)) * TLEN
                                + (size_t)(slist[sv] * CS + kk * 32) + c16;
#pragma unroll
            for (int t = 0; t < 4; ++t)
                gl_lds16(gsrc + (size_t)((w - 2) * 64 + t * 16 + rr) * TLEN,
                         &Bs[bf][((w - 2) * 64 + t * 16) * 32]);
        }
    };

    floatx4 accT[4][4], accP[4][4];
#pragma unroll
    for (int rt = 0; rt < 4; ++rt)
#pragma unroll
        for (int ct = 0; ct < 4; ++ct) accT[rt][ct] = (floatx4){0.f, 0.f, 0.f, 0.f};

    stage(0, 0);
    __syncthreads();

    int buf = 0;
    for (int st = 0; st < NS; ++st) {
        if (st + 1 < NS) stage(st + 1, buf ^ 1);

        if ((st & 3) == 0) {
#pragma unroll
            for (int rt = 0; rt < 4; ++rt)
#pragma unroll
                for (int ct = 0; ct < 4; ++ct) accP[rt][ct] = (floatx4){0.f, 0.f, 0.f, 0.f};
        }

        short8 bh[4];
#pragma unroll
        for (int ct = 0; ct < 4; ++ct) {
            int e = wc * 64 + ct * 16 + l15;
            bh[ct] = *(const short8*)&Bs[buf][e * 32 + quad * 8];
        }
#pragma unroll
        for (int rt = 0; rt < 4; ++rt) {
            int r = wr * 64 + rt * 16 + l15;
            short8 ah = *(const short8*)&As[buf][r * 32 + quad * 8];
#pragma unroll
            for (int ct = 0; ct < 4; ++ct)
                accP[rt][ct] = __builtin_amdgcn_mfma_f32_16x16x32_bf16(ah, bh[ct], accP[rt][ct], 0, 0, 0);
        }

        if ((st & 3) == 3) {
            float wcur = swei[st >> 2];
#pragma unroll
            for (int rt = 0; rt < 4; ++rt)
#pragma unroll
                for (int ct = 0; ct < 4; ++ct)
#pragma unroll
                    for (int reg = 0; reg < 4; ++reg)
                        accT[rt][ct][reg] += wcur * accP[rt][ct][reg];
        }
        __syncthreads();
        buf ^= 1;
    }

#pragma unroll
    for (int rt = 0; rt < 4; ++rt)
#pragma unroll
        for (int ct = 0; ct < 4; ++ct) {
#pragma unroll
            for (int reg = 0; reg < 4; ++reg) {
                int row = wr * 64 + rt * 16 + quad * 4 + reg;
                int col = wc * 64 + ct * 16 + l15;
                size_t o = ((size_t)(b * TLEN + n * CS + row)) * EDIM + e0 + col;
                out[o] = accT[rt][ct][reg] + x[o];
            }
        }
}

// ---------------------------------------------------------------------------
extern "C" void kernel_launch(void* const* d_in, const int* in_sizes, int n_in,
                              void* d_out, int out_size, void* d_ws, size_t ws_size,
                              hipStream_t stream) {
    const float* x  = (const float*)d_in[0];   // [2, 8192, 256] fp32
    const float* dp = (const float*)d_in[1];   // [128, 1024] fp32
    float* out = (float*)d_out;

    char* ws = (char*)d_ws;
    short* cn_hi  = (short*)(ws);                       // 8 MB
    short* cn_lo  = (short*)(ws + (8u << 20));          // 8 MB
    short* xt_hi  = (short*)(ws + (16u << 20));         // 8 MB
    short* dp_hi  = (short*)(ws + (24u << 20));         // 256 KB
    float* scores = (float*)(ws + (25u << 20));         // 32 KB
    int*   ext_idx = (int*)  (ws + (25u << 20) + 32768);
    float* ext_w   = (float*)(ws + (25u << 20) + 32768 + 4096);

    normsplit_kernel<<<dim3(NBATCH * TLEN / 4), 256, 0, stream>>>(x, cn_hi, cn_lo);
    xt_split_kernel <<<dim3(EDIM / 64, TLEN / 64, NBATCH), 256, 0, stream>>>(x, xt_hi);
    dp_split_kernel <<<dim3(CS * LEXT / 1024), 256, 0, stream>>>(dp, dp_hi);
    scores_mfma     <<<dim3(126, NBATCH), 256, 0, stream>>>(cn_hi, cn_lo, scores);
    topk_kernel     <<<1, 128, 0, stream>>>(scores, ext_idx, ext_w);
    out_mfma        <<<dim3(2, NCHUNK, NBATCH), 256, 0, stream>>>(x, dp_hi, xt_hi,
                                                                  ext_idx, ext_w, out);
}